// Round 8
// baseline (150.508 us; speedup 1.0000x reference)
//
#include <hip/hip_runtime.h>
#include <math.h>

#define B_  16
#define C_  256
#define S_  1024
#define NH  4
#define DK  64
#define P3  768   // 3*NH*DK
#define ND  256   // NH*DK

typedef unsigned short u16;
typedef unsigned int   u32;
typedef float  f32x4  __attribute__((ext_vector_type(4)));
typedef short  bf16x8 __attribute__((ext_vector_type(8)));

#define MFMA16(a, b, c) __builtin_amdgcn_mfma_f32_16x16x32_bf16(a, b, c, 0, 0, 0)

// fold softmax scale*log2(e) into q at projection time
#define QSCALE 0.1803368801111137f   // 0.125 * 1.44269504

__device__ __forceinline__ u16 f2bf(float f) {
    union { float f; u32 u; } x; x.f = f;
    u32 r = x.u + 0x7fffu + ((x.u >> 16) & 1u);   // RNE
    return (u16)(r >> 16);
}

// async global->LDS, 16B per lane; LDS dest is wave-uniform base + lane*16
__device__ __forceinline__ void stage16(const u16* g, u16* l) {
    __builtin_amdgcn_global_load_lds(
        (const __attribute__((address_space(1))) void*)g,
        (__attribute__((address_space(3))) void*)l, 16, 0, 0);
}

// ---------------------------------------------------------------------------
// Tiled transpose + fp32->bf16: src[z][R][Cc] -> dst[z][Cc][R]  (for x)
// ---------------------------------------------------------------------------
__global__ __launch_bounds__(256) void transpose_cvt(
    const float* __restrict__ src, u16* __restrict__ dst, int R, int Cc)
{
    __shared__ float T[64][65];
    const int tid = threadIdx.x;
    const int c0 = blockIdx.x * 64, r0 = blockIdx.y * 64, z = blockIdx.z;
    src += (size_t)z * R * Cc;
    dst += (size_t)z * R * Cc;

    const int l64 = tid & 63, rr0 = tid >> 6;
    #pragma unroll
    for (int t = 0; t < 16; ++t) {
        int rr = rr0 + t * 4;
        T[rr][l64] = src[(size_t)(r0 + rr) * Cc + c0 + l64];
    }
    __syncthreads();
    const int rp = tid & 31;
    const int cb = tid >> 5;
    #pragma unroll
    for (int t = 0; t < 8; ++t) {
        int c = cb + t * 8;
        u32 lo = f2bf(T[2 * rp][c]);
        u32 hi = f2bf(T[2 * rp + 1][c]);
        *(u32*)&dst[(size_t)(c0 + c) * R + r0 + 2 * rp] = lo | (hi << 16);
    }
}

// Both weight transposes in one launch: z=0 -> wp (256x768), z=1 -> wo (256x256)
__global__ __launch_bounds__(256) void transpose_w(
    const float* __restrict__ wp, u16* __restrict__ wpT,
    const float* __restrict__ wo, u16* __restrict__ woT)
{
    const int z = blockIdx.z;
    const int Cc = z ? 256 : 768;
    if ((int)blockIdx.x * 64 >= Cc) return;
    const float* src = z ? wo : wp;
    u16* dst = z ? woT : wpT;
    const int R = 256;

    __shared__ float T[64][65];
    const int tid = threadIdx.x;
    const int c0 = blockIdx.x * 64, r0 = blockIdx.y * 64;

    const int l64 = tid & 63, rr0 = tid >> 6;
    #pragma unroll
    for (int t = 0; t < 16; ++t) {
        int rr = rr0 + t * 4;
        T[rr][l64] = src[(size_t)(r0 + rr) * Cc + c0 + l64];
    }
    __syncthreads();
    const int rp = tid & 31;
    const int cb = tid >> 5;
    #pragma unroll
    for (int t = 0; t < 8; ++t) {
        int c = cb + t * 8;
        u32 lo = f2bf(T[2 * rp][c]);
        u32 hi = f2bf(T[2 * rp + 1][c]);
        *(u32*)&dst[(size_t)(c0 + c) * R + r0 + 2 * rp] = lo | (hi << 16);
    }
}

// ---------------------------------------------------------------------------
// QKV projection: 128(M=s) x 64(N=n) tile, 4 waves x (32x64), BK=128.
// XCD swizzle: the 12 n0-blocks sharing one xt slice land on one XCD.
// q gets QSCALE folded in. v stored TRANSPOSED [bh][dk][s] (plain order).
// ---------------------------------------------------------------------------
__global__ __launch_bounds__(256) void qkv_mfma(
    const u16* __restrict__ xt, const u16* __restrict__ wpT,
    const float* __restrict__ bp, u16* __restrict__ qo,
    u16* __restrict__ ko, u16* __restrict__ vo)
{
    __shared__ __align__(16) u16 SM[24576];   // As 16384 (128x128) + Bs 8192 (64x128)
    u16* As = SM;
    u16* Bs = SM + 16384;

    const int tid = threadIdx.x;
    const int w = tid >> 6, lane = tid & 63;
    const int n_ = lane & 15, quad = lane >> 4;

    // swizzle: 1536 blocks = 8 xcd x (12 n0 x 16 sb-group)
    const int id = blockIdx.x;
    const int xcd = id & 7, g = id >> 3;
    const int n0 = (g % 12) * 64;
    const int sb = xcd * 16 + g / 12;        // [0,128)
    const int s0 = (sb & 7) * 128, b = sb >> 3;

    const u16* ar0 = xt + ((size_t)b * S_ + s0 + (2 * w + 0) * 16 + n_) * C_ + quad * 8;
    const u16* ar1 = xt + ((size_t)b * S_ + s0 + (2 * w + 1) * 16 + n_) * C_ + quad * 8;
    const u16* br  = wpT + (size_t)(n0 + w * 16 + n_) * C_ + quad * 8;

    f32x4 acc[2][4];
    #pragma unroll
    for (int am = 0; am < 2; ++am)
        #pragma unroll
        for (int nf = 0; nf < 4; ++nf)
            #pragma unroll
            for (int r = 0; r < 4; ++r) acc[am][nf][r] = 0.f;

    #pragma unroll
    for (int kb = 0; kb < 2; ++kb) {
        const int kcb = kb * 128;
        __syncthreads();
        #pragma unroll
        for (int kc = 0; kc < 4; ++kc) {
            stage16(ar0 + kcb + kc * 32, As + ((2 * w + 0) * 4 + kc) * 512);
            stage16(ar1 + kcb + kc * 32, As + ((2 * w + 1) * 4 + kc) * 512);
            stage16(br  + kcb + kc * 32, Bs + (w * 4 + kc) * 512);
        }
        __syncthreads();
        #pragma unroll
        for (int kc = 0; kc < 4; ++kc) {
            bf16x8 af0 = *(const bf16x8*)&As[((2 * w + 0) * 4 + kc) * 512 + lane * 8];
            bf16x8 af1 = *(const bf16x8*)&As[((2 * w + 1) * 4 + kc) * 512 + lane * 8];
            #pragma unroll
            for (int nf = 0; nf < 4; ++nf) {
                bf16x8 bf = *(const bf16x8*)&Bs[(nf * 4 + kc) * 512 + lane * 8];
                acc[0][nf] = MFMA16(af0, bf, acc[0][nf]);
                acc[1][nf] = MFMA16(af1, bf, acc[1][nf]);
            }
        }
    }

    const int hd = n0 / 192, rem = n0 % 192, which = rem / 64;
    const int bh = b * NH + hd;
    float bias[4];
    #pragma unroll
    for (int nf = 0; nf < 4; ++nf) bias[nf] = bp[n0 + nf * 16 + n_];
    const float sc = (which == 0) ? QSCALE : 1.f;

    __syncthreads();   // done with As/Bs, reuse SM for epilogue
    if (which < 2) {
        u16* Cs = SM;                      // [128][72]
        #pragma unroll
        for (int am = 0; am < 2; ++am) {
            int row0 = w * 32 + am * 16 + quad * 4;
            #pragma unroll
            for (int nf = 0; nf < 4; ++nf)
                #pragma unroll
                for (int r = 0; r < 4; ++r)
                    Cs[(row0 + r) * 72 + nf * 16 + n_] =
                        f2bf((acc[am][nf][r] + bias[nf]) * sc);
        }
        __syncthreads();
        u16* dst = (which == 0) ? qo : ko;
        #pragma unroll
        for (int t = 0; t < 4; ++t) {
            int ii = tid + t * 256;
            int row = ii >> 3, c8 = (ii & 7) * 8;
            *(bf16x8*)&dst[((size_t)bh * S_ + s0 + row) * DK + c8] =
                *(const bf16x8*)&Cs[row * 72 + c8];
        }
    } else {
        u16* Cs = SM;                      // [64][136] (dk-major, plain s cols)
        #pragma unroll
        for (int am = 0; am < 2; ++am) {
            int colb = w * 32 + am * 16 + quad * 4;
            #pragma unroll
            for (int nf = 0; nf < 4; ++nf)
                #pragma unroll
                for (int r = 0; r < 4; ++r)
                    Cs[(nf * 16 + n_) * 136 + colb + r] =
                        f2bf(acc[am][nf][r] + bias[nf]);
        }
        __syncthreads();
        #pragma unroll
        for (int t = 0; t < 4; ++t) {
            int ii = tid + t * 256;
            int row = ii >> 4, c8 = (ii & 15) * 8;
            *(bf16x8*)&vo[((size_t)bh * DK + row) * S_ + s0 + c8] =
                *(const bf16x8*)&Cs[row * 136 + c8];
        }
    }
}

// ---------------------------------------------------------------------------
// Flash attention: block = 128 q (4 waves x 32 q), 128-KEY tiles (8 iters),
// SINGLE-buffered staging (R6-proven barrier discipline), no-max softmax,
// S^T trick with extended kappa so P repack is pure registers:
//   kappa(nb, n_) = (nb>>1)*32 + 8*(n_>>2) + 4*(nb&1) + (n_&3)
//   C-pos (nb,quad,r) key = (nb>>1)*32 + 8*quad + 4*(nb&1) + r
//   PV slot mf*32 + quad*8 + j  (mf=nb>>1, j=4*(nb&1)+r)  -> identity
//   pa[mf] = {tr[2mf][0..3], tr[2mf+1][0..3]}
// PV: O^T = V^T (A) * P^T (B); V staged un-permuted in 4 chunks/wave.
// ---------------------------------------------------------------------------
__global__ __launch_bounds__(256) void attn_mfma(
    const u16* __restrict__ q, const u16* __restrict__ k,
    const u16* __restrict__ vt, u16* __restrict__ obf)
{
    __shared__ __align__(16) u16 SM[16384];   // Ks 8192 (128x64) + Vs 8192 (64x128)
    u16* Ks = SM;
    u16* Vs = SM + 8192;

    const int tid = threadIdx.x;
    const int w = tid >> 6, lane = tid & 63;
    const int n_ = lane & 15, quad = lane >> 4;

    // swizzle: 512 blocks = 8 xcd x (8 i0 x 8 bh-group)
    const int id = blockIdx.x;
    const int xcd = id & 7, g = id >> 3;
    const int i0 = (g % 8) * 128;
    const int bh = xcd * 8 + g / 8;          // [0,64)
    const int hd = bh & 3, b = bh >> 2;

    // Q fragments (B-operand; scale pre-folded): query = i0 + w*32 + am*16 + n_
    bf16x8 qf[2][2];
    #pragma unroll
    for (int am = 0; am < 2; ++am) {
        const u16* qrow = q + ((size_t)bh * S_ + i0 + w * 32 + am * 16 + n_) * DK;
        qf[am][0] = *(const bf16x8*)&qrow[quad * 8];
        qf[am][1] = *(const bf16x8*)&qrow[32 + quad * 8];
    }

    // K staging: wave w stages nb=2w (keys k0+) and nb=2w+1 (keys k0+4+)
    const int k0 = 32 * w + 8 * (n_ >> 2) + (n_ & 3);
    const u16* kb0 = k + ((size_t)bh * S_ + k0) * DK + quad * 8;
    const u16* kb1 = kb0 + 4 * DK;
    const u16* vb  = vt + ((size_t)bh * DK + w * 16 + n_) * S_ + quad * 8;

    float lsum[2] = {0.f, 0.f};
    f32x4 oacc[2][4];
    #pragma unroll
    for (int am = 0; am < 2; ++am)
        #pragma unroll
        for (int nd = 0; nd < 4; ++nd)
            #pragma unroll
            for (int r = 0; r < 4; ++r) oacc[am][nd][r] = 0.f;

    for (int jt = 0; jt < S_; jt += 128) {
        __syncthreads();
        stage16(kb0 + (size_t)jt * DK,      Ks + (2 * w + 0) * 1024);
        stage16(kb0 + (size_t)jt * DK + 32, Ks + (2 * w + 0) * 1024 + 512);
        stage16(kb1 + (size_t)jt * DK,      Ks + (2 * w + 1) * 1024);
        stage16(kb1 + (size_t)jt * DK + 32, Ks + (2 * w + 1) * 1024 + 512);
        #pragma unroll
        for (int mf = 0; mf < 4; ++mf)
            stage16(vb + jt + mf * 32, Vs + (w * 4 + mf) * 512);
        __syncthreads();

        // S^T = K Q^T : 8 key-blocks x 2 am
        f32x4 sb[2][8];
        #pragma unroll
        for (int nb = 0; nb < 8; ++nb) {
            bf16x8 kf0 = *(const bf16x8*)&Ks[nb * 1024 + lane * 8];
            bf16x8 kf1 = *(const bf16x8*)&Ks[nb * 1024 + 512 + lane * 8];
            #pragma unroll
            for (int am = 0; am < 2; ++am) {
                f32x4 a; a[0] = a[1] = a[2] = a[3] = 0.f;
                a = MFMA16(kf0, qf[am][0], a);
                a = MFMA16(kf1, qf[am][1], a);
                sb[am][nb] = a;
            }
        }

        // exp2, truncate to bf16, per-lane scalar sum, register repack
        bf16x8 pa[2][4];
        #pragma unroll
        for (int am = 0; am < 2; ++am) {
            u32 tr[8][4];
            #pragma unroll
            for (int nb = 0; nb < 8; ++nb)
                #pragma unroll
                for (int r = 0; r < 4; ++r) {
                    float p = exp2f(sb[am][nb][r]);
                    u32 bits = __float_as_uint(p) & 0xffff0000u;
                    lsum[am] += __uint_as_float(bits);
                    tr[nb][r] = bits;
                }
            #pragma unroll
            for (int mf = 0; mf < 4; ++mf) {
                union { bf16x8 v; u32 u[4]; } pk;
                pk.u[0] = (tr[2 * mf][0] >> 16) | tr[2 * mf][1];
                pk.u[1] = (tr[2 * mf][2] >> 16) | tr[2 * mf][3];
                pk.u[2] = (tr[2 * mf + 1][0] >> 16) | tr[2 * mf + 1][1];
                pk.u[3] = (tr[2 * mf + 1][2] >> 16) | tr[2 * mf + 1][3];
                pa[am][mf] = pk.v;
            }
        }

        // O^T += V^T P^T : A = V^T frags (slot = actual key offset), B = pa
        #pragma unroll
        for (int nd = 0; nd < 4; ++nd)
            #pragma unroll
            for (int mf = 0; mf < 4; ++mf) {
                bf16x8 vf = *(const bf16x8*)&Vs[(nd * 4 + mf) * 512 + lane * 8];
                #pragma unroll
                for (int am = 0; am < 2; ++am)
                    oacc[am][nd] = MFMA16(vf, pa[am][mf], oacc[am][nd]);
            }
    }

    // total = sum over 4 quads (all in-lane values are for query n_)
    float inv[2];
    #pragma unroll
    for (int am = 0; am < 2; ++am) {
        float s = lsum[am];
        s += __shfl_xor(s, 16);
        s += __shfl_xor(s, 32);
        inv[am] = 1.f / s;
    }

    // epilogue: O^T[dk=nd*16+quad*4+r][query=n_] -> eb[query-local][dk]
    __syncthreads();
    u16* eb = SM + w * 2304;   // [32][72]
    #pragma unroll
    for (int am = 0; am < 2; ++am)
        #pragma unroll
        for (int nd = 0; nd < 4; ++nd) {
            uint2 uv;
            uv.x = (u32)f2bf(oacc[am][nd][0] * inv[am]) |
                   ((u32)f2bf(oacc[am][nd][1] * inv[am]) << 16);
            uv.y = (u32)f2bf(oacc[am][nd][2] * inv[am]) |
                   ((u32)f2bf(oacc[am][nd][3] * inv[am]) << 16);
            *(uint2*)&eb[(am * 16 + n_) * 72 + nd * 16 + quad * 4] = uv;
        }
    __syncthreads();
    #pragma unroll
    for (int t = 0; t < 4; ++t) {
        int ii = lane + t * 64;
        int row = ii >> 3, c8 = (ii & 7) * 8;
        *(bf16x8*)&obf[((size_t)b * S_ + i0 + w * 32 + row) * ND + hd * DK + c8] =
            *(const bf16x8*)&eb[row * 72 + c8];
    }
}

// ---------------------------------------------------------------------------
// Out projection: A = woT (M=c=64), B = obf (N=s=128), BK=128.
// XCD swizzle: the 4 c0-blocks sharing one obf slice land on one XCD.
// C[c][s] layout -> direct coalesced stores out[b][c][s] (+bias+residual).
// ---------------------------------------------------------------------------
__global__ __launch_bounds__(256) void out_proj_mfma(
    const u16* __restrict__ obf, const u16* __restrict__ woT,
    const float* __restrict__ bo, const float* __restrict__ x,
    float* __restrict__ out)
{
    __shared__ __align__(16) u16 SM[24576];   // Bs 16384 (128x128) + As 8192 (64x128)
    u16* Bs = SM;
    u16* As = SM + 16384;

    const int tid = threadIdx.x;
    const int w = tid >> 6, lane = tid & 63;
    const int n_ = lane & 15, quad = lane >> 4;

    // swizzle: 512 blocks = 8 xcd x (4 c0 x 16 sb-group)
    const int id = blockIdx.x;
    const int xcd = id & 7, g = id >> 3;
    const int c0 = (g % 4) * 64;
    const int sbi = xcd * 16 + g / 4;        // [0,128)
    const int s0 = (sbi & 7) * 128, b = sbi >> 3;

    const u16* ar  = woT + (size_t)(c0 + w * 16 + n_) * ND + quad * 8;
    const u16* br0 = obf + ((size_t)b * S_ + s0 + (2 * w + 0) * 16 + n_) * ND + quad * 8;
    const u16* br1 = obf + ((size_t)b * S_ + s0 + (2 * w + 1) * 16 + n_) * ND + quad * 8;

    f32x4 acc[2][4];
    #pragma unroll
    for (int nf = 0; nf < 2; ++nf)
        #pragma unroll
        for (int mb = 0; mb < 4; ++mb)
            #pragma unroll
            for (int r = 0; r < 4; ++r) acc[nf][mb][r] = 0.f;

    #pragma unroll
    for (int kb = 0; kb < 2; ++kb) {
        const int kcb = kb * 128;
        __syncthreads();
        #pragma unroll
        for (int kc = 0; kc < 4; ++kc) {
            stage16(ar  + kcb + kc * 32, As + (w * 4 + kc) * 512);
            stage16(br0 + kcb + kc * 32, Bs + ((2 * w + 0) * 4 + kc) * 512);
            stage16(br1 + kcb + kc * 32, Bs + ((2 * w + 1) * 4 + kc) * 512);
        }
        __syncthreads();
        #pragma unroll
        for (int kc = 0; kc < 4; ++kc) {
            bf16x8 bf0 = *(const bf16x8*)&Bs[((2 * w + 0) * 4 + kc) * 512 + lane * 8];
            bf16x8 bf1 = *(const bf16x8*)&Bs[((2 * w + 1) * 4 + kc) * 512 + lane * 8];
            #pragma unroll
            for (int mb = 0; mb < 4; ++mb) {
                bf16x8 af = *(const bf16x8*)&As[(mb * 4 + kc) * 512 + lane * 8];
                acc[0][mb] = MFMA16(af, bf0, acc[0][mb]);
                acc[1][mb] = MFMA16(af, bf1, acc[1][mb]);
            }
        }
    }

    // direct epilogue: c = c0+mb*16+quad*4+r, s = s0+w*32+nf*16+n_
    #pragma unroll
    for (int mb = 0; mb < 4; ++mb)
        #pragma unroll
        for (int r = 0; r < 4; ++r) {
            int c = c0 + mb * 16 + quad * 4 + r;
            float bias = bo[c];
            #pragma unroll
            for (int nf = 0; nf < 2; ++nf) {
                size_t idx = ((size_t)b * C_ + c) * S_ + s0 + w * 32 + nf * 16 + n_;
                out[idx] = acc[nf][mb][r] + bias + x[idx];
            }
        }
}

// ---------------------------------------------------------------------------
extern "C" void kernel_launch(void* const* d_in, const int* in_sizes, int n_in,
                              void* d_out, int out_size, void* d_ws, size_t ws_size,
                              hipStream_t stream) {
    const float* x  = (const float*)d_in[0];
    const float* wp = (const float*)d_in[1];
    const float* bp = (const float*)d_in[2];
    const float* wo = (const float*)d_in[3];
    const float* bo = (const float*)d_in[4];
    float* out = (float*)d_out;

    const size_t QKV_E = (size_t)B_ * NH * S_ * DK;   // 4 Mi
    u16* q   = (u16*)d_ws;
    u16* kk  = q   + QKV_E;
    u16* vtp = kk  + QKV_E;
    u16* obf = vtp + QKV_E;                            // B*S*ND
    u16* xt  = obf + (size_t)B_ * S_ * ND;             // B*S*C
    u16* wpT = xt  + (size_t)B_ * S_ * C_;             // P3*C
    u16* woT = wpT + (size_t)P3 * C_;                  // C*ND

    transpose_cvt<<<dim3(S_ / 64, C_ / 64, B_), 256, 0, stream>>>(x, xt, C_, S_);
    transpose_w  <<<dim3(12, 4, 2),             256, 0, stream>>>(wp, wpT, wo, woT);
    qkv_mfma     <<<dim3(1536), 256, 0, stream>>>(xt, wpT, bp, q, kk, vtp);
    attn_mfma    <<<dim3(512),  256, 0, stream>>>(q, kk, vtp, obf);
    out_proj_mfma<<<dim3(512),  256, 0, stream>>>(obf, woT, bo, x, out);
}

// Round 9
// 148.497 us; speedup vs baseline: 1.0135x; 1.0135x over previous
//
#include <hip/hip_runtime.h>
#include <math.h>

#define B_  16
#define C_  256
#define S_  1024
#define NH  4
#define DK  64
#define P3  768   // 3*NH*DK
#define ND  256   // NH*DK

typedef unsigned short u16;
typedef unsigned int   u32;
typedef float  f32x4  __attribute__((ext_vector_type(4)));
typedef short  bf16x8 __attribute__((ext_vector_type(8)));

#define MFMA16(a, b, c) __builtin_amdgcn_mfma_f32_16x16x32_bf16(a, b, c, 0, 0, 0)

// fold softmax scale*log2(e) into q at projection time
#define QSCALE 0.1803368801111137f   // 0.125 * 1.44269504

__device__ __forceinline__ u16 f2bf(float f) {
    union { float f; u32 u; } x; x.f = f;
    u32 r = x.u + 0x7fffu + ((x.u >> 16) & 1u);   // RNE
    return (u16)(r >> 16);
}

// async global->LDS, 16B per lane; LDS dest is wave-uniform base + lane*16
__device__ __forceinline__ void stage16(const u16* g, u16* l) {
    __builtin_amdgcn_global_load_lds(
        (const __attribute__((address_space(1))) void*)g,
        (__attribute__((address_space(3))) void*)l, 16, 0, 0);
}

// ---------------------------------------------------------------------------
// Tiled transpose + fp32->bf16: src[z][R][Cc] -> dst[z][Cc][R]  (for x)
// ---------------------------------------------------------------------------
__global__ __launch_bounds__(256) void transpose_cvt(
    const float* __restrict__ src, u16* __restrict__ dst, int R, int Cc)
{
    __shared__ float T[64][65];
    const int tid = threadIdx.x;
    const int c0 = blockIdx.x * 64, r0 = blockIdx.y * 64, z = blockIdx.z;
    src += (size_t)z * R * Cc;
    dst += (size_t)z * R * Cc;

    const int l64 = tid & 63, rr0 = tid >> 6;
    #pragma unroll
    for (int t = 0; t < 16; ++t) {
        int rr = rr0 + t * 4;
        T[rr][l64] = src[(size_t)(r0 + rr) * Cc + c0 + l64];
    }
    __syncthreads();
    const int rp = tid & 31;
    const int cb = tid >> 5;
    #pragma unroll
    for (int t = 0; t < 8; ++t) {
        int c = cb + t * 8;
        u32 lo = f2bf(T[2 * rp][c]);
        u32 hi = f2bf(T[2 * rp + 1][c]);
        *(u32*)&dst[(size_t)(c0 + c) * R + r0 + 2 * rp] = lo | (hi << 16);
    }
}

// Both weight transposes in one launch: z=0 -> wp (256x768), z=1 -> wo (256x256)
__global__ __launch_bounds__(256) void transpose_w(
    const float* __restrict__ wp, u16* __restrict__ wpT,
    const float* __restrict__ wo, u16* __restrict__ woT)
{
    const int z = blockIdx.z;
    const int Cc = z ? 256 : 768;
    if ((int)blockIdx.x * 64 >= Cc) return;
    const float* src = z ? wo : wp;
    u16* dst = z ? woT : wpT;
    const int R = 256;

    __shared__ float T[64][65];
    const int tid = threadIdx.x;
    const int c0 = blockIdx.x * 64, r0 = blockIdx.y * 64;

    const int l64 = tid & 63, rr0 = tid >> 6;
    #pragma unroll
    for (int t = 0; t < 16; ++t) {
        int rr = rr0 + t * 4;
        T[rr][l64] = src[(size_t)(r0 + rr) * Cc + c0 + l64];
    }
    __syncthreads();
    const int rp = tid & 31;
    const int cb = tid >> 5;
    #pragma unroll
    for (int t = 0; t < 8; ++t) {
        int c = cb + t * 8;
        u32 lo = f2bf(T[2 * rp][c]);
        u32 hi = f2bf(T[2 * rp + 1][c]);
        *(u32*)&dst[(size_t)(c0 + c) * R + r0 + 2 * rp] = lo | (hi << 16);
    }
}

// ---------------------------------------------------------------------------
// QKV projection: 128(M=s) x 64(N=n) tile, 4 waves x (32x64), BK=128.
// XCD swizzle: the 12 n0-blocks sharing one xt slice land on one XCD.
// q gets QSCALE folded in. v stored TRANSPOSED [bh][dk][s] (plain order).
// ---------------------------------------------------------------------------
__global__ __launch_bounds__(256) void qkv_mfma(
    const u16* __restrict__ xt, const u16* __restrict__ wpT,
    const float* __restrict__ bp, u16* __restrict__ qo,
    u16* __restrict__ ko, u16* __restrict__ vo)
{
    __shared__ __align__(16) u16 SM[24576];   // As 16384 (128x128) + Bs 8192 (64x128)
    u16* As = SM;
    u16* Bs = SM + 16384;

    const int tid = threadIdx.x;
    const int w = tid >> 6, lane = tid & 63;
    const int n_ = lane & 15, quad = lane >> 4;

    // swizzle: 1536 blocks = 8 xcd x (12 n0 x 16 sb-group)
    const int id = blockIdx.x;
    const int xcd = id & 7, g = id >> 3;
    const int n0 = (g % 12) * 64;
    const int sb = xcd * 16 + g / 12;        // [0,128)
    const int s0 = (sb & 7) * 128, b = sb >> 3;

    const u16* ar0 = xt + ((size_t)b * S_ + s0 + (2 * w + 0) * 16 + n_) * C_ + quad * 8;
    const u16* ar1 = xt + ((size_t)b * S_ + s0 + (2 * w + 1) * 16 + n_) * C_ + quad * 8;
    const u16* br  = wpT + (size_t)(n0 + w * 16 + n_) * C_ + quad * 8;

    f32x4 acc[2][4];
    #pragma unroll
    for (int am = 0; am < 2; ++am)
        #pragma unroll
        for (int nf = 0; nf < 4; ++nf)
            #pragma unroll
            for (int r = 0; r < 4; ++r) acc[am][nf][r] = 0.f;

    #pragma unroll
    for (int kb = 0; kb < 2; ++kb) {
        const int kcb = kb * 128;
        __syncthreads();
        #pragma unroll
        for (int kc = 0; kc < 4; ++kc) {
            stage16(ar0 + kcb + kc * 32, As + ((2 * w + 0) * 4 + kc) * 512);
            stage16(ar1 + kcb + kc * 32, As + ((2 * w + 1) * 4 + kc) * 512);
            stage16(br  + kcb + kc * 32, Bs + (w * 4 + kc) * 512);
        }
        __syncthreads();
        #pragma unroll
        for (int kc = 0; kc < 4; ++kc) {
            bf16x8 af0 = *(const bf16x8*)&As[((2 * w + 0) * 4 + kc) * 512 + lane * 8];
            bf16x8 af1 = *(const bf16x8*)&As[((2 * w + 1) * 4 + kc) * 512 + lane * 8];
            #pragma unroll
            for (int nf = 0; nf < 4; ++nf) {
                bf16x8 bf = *(const bf16x8*)&Bs[(nf * 4 + kc) * 512 + lane * 8];
                acc[0][nf] = MFMA16(af0, bf, acc[0][nf]);
                acc[1][nf] = MFMA16(af1, bf, acc[1][nf]);
            }
        }
    }

    const int hd = n0 / 192, rem = n0 % 192, which = rem / 64;
    const int bh = b * NH + hd;
    float bias[4];
    #pragma unroll
    for (int nf = 0; nf < 4; ++nf) bias[nf] = bp[n0 + nf * 16 + n_];
    const float sc = (which == 0) ? QSCALE : 1.f;

    __syncthreads();   // done with As/Bs, reuse SM for epilogue
    if (which < 2) {
        u16* Cs = SM;                      // [128][72]
        #pragma unroll
        for (int am = 0; am < 2; ++am) {
            int row0 = w * 32 + am * 16 + quad * 4;
            #pragma unroll
            for (int nf = 0; nf < 4; ++nf)
                #pragma unroll
                for (int r = 0; r < 4; ++r)
                    Cs[(row0 + r) * 72 + nf * 16 + n_] =
                        f2bf((acc[am][nf][r] + bias[nf]) * sc);
        }
        __syncthreads();
        u16* dst = (which == 0) ? qo : ko;
        #pragma unroll
        for (int t = 0; t < 4; ++t) {
            int ii = tid + t * 256;
            int row = ii >> 3, c8 = (ii & 7) * 8;
            *(bf16x8*)&dst[((size_t)bh * S_ + s0 + row) * DK + c8] =
                *(const bf16x8*)&Cs[row * 72 + c8];
        }
    } else {
        u16* Cs = SM;                      // [64][136] (dk-major, plain s cols)
        #pragma unroll
        for (int am = 0; am < 2; ++am) {
            int colb = w * 32 + am * 16 + quad * 4;
            #pragma unroll
            for (int nf = 0; nf < 4; ++nf)
                #pragma unroll
                for (int r = 0; r < 4; ++r)
                    Cs[(nf * 16 + n_) * 136 + colb + r] =
                        f2bf(acc[am][nf][r] + bias[nf]);
        }
        __syncthreads();
        #pragma unroll
        for (int t = 0; t < 4; ++t) {
            int ii = tid + t * 256;
            int row = ii >> 4, c8 = (ii & 15) * 8;
            *(bf16x8*)&vo[((size_t)bh * DK + row) * S_ + s0 + c8] =
                *(const bf16x8*)&Cs[row * 136 + c8];
        }
    }
}

// ---------------------------------------------------------------------------
// Flash attention v2: block = 64 q (4 waves x 16 q each), 64-key tiles,
// 16 iters. Grid 1024 -> 4 blocks/CU, 16 waves/CU (2x R8 occupancy).
// S^T trick, kappa-permuted K staging (R8-proven mapping, nb in [0,4)):
//   kappa(nb, n_) = (nb>>1)*32 + 8*(n_>>2) + 4*(nb&1) + (n_&3)
//   pa[mf] = {tr[2mf][0..3], tr[2mf+1][0..3]}, mf in {0,1}
// PV: O^T = V^T (A, un-permuted) * P^T (B). No-max softmax, per-lane sums.
// ---------------------------------------------------------------------------
__global__ __launch_bounds__(256) void attn_mfma(
    const u16* __restrict__ q, const u16* __restrict__ k,
    const u16* __restrict__ vt, u16* __restrict__ obf)
{
    __shared__ __align__(16) u16 SM[8192];   // Ks 4096 (64x64) + Vs 4096 (64x64)
    u16* Ks = SM;
    u16* Vs = SM + 4096;

    const int tid = threadIdx.x;
    const int w = tid >> 6, lane = tid & 63;
    const int n_ = lane & 15, quad = lane >> 4;

    // swizzle: 1024 blocks = 8 xcd x (16 i0 x 8 bh-group)
    const int id = blockIdx.x;
    const int xcd = id & 7, g = id >> 3;
    const int i0 = (g % 16) * 64;
    const int bh = xcd * 8 + g / 16;         // [0,64)
    const int hd = bh & 3, b = bh >> 2;

    // Q fragments (B-operand; scale pre-folded): query = i0 + w*16 + n_
    const u16* qrow = q + ((size_t)bh * S_ + i0 + w * 16 + n_) * DK;
    bf16x8 qf0 = *(const bf16x8*)&qrow[quad * 8];
    bf16x8 qf1 = *(const bf16x8*)&qrow[32 + quad * 8];

    // K staging: wave w stages nb-block w with kappa permutation
    const int kappa = (w >> 1) * 32 + 8 * (n_ >> 2) + 4 * (w & 1) + (n_ & 3);
    const u16* kb = k + ((size_t)bh * S_ + kappa) * DK + quad * 8;
    // V staging: wave w stages V^T dk-rows w*16+n_, un-permuted
    const u16* vb = vt + ((size_t)bh * DK + w * 16 + n_) * S_ + quad * 8;

    float lsum = 0.f;
    f32x4 oacc[4];
    #pragma unroll
    for (int nd = 0; nd < 4; ++nd)
        #pragma unroll
        for (int r = 0; r < 4; ++r) oacc[nd][r] = 0.f;

    for (int jt = 0; jt < S_; jt += 64) {
        __syncthreads();
        stage16(kb + (size_t)jt * DK,      Ks + w * 1024);
        stage16(kb + (size_t)jt * DK + 32, Ks + w * 1024 + 512);
        stage16(vb + jt,                   Vs + (w * 2 + 0) * 512);
        stage16(vb + jt + 32,              Vs + (w * 2 + 1) * 512);
        __syncthreads();

        // S^T = K Q^T : 4 key-blocks (16 key-slots each)
        f32x4 sb[4];
        #pragma unroll
        for (int nb = 0; nb < 4; ++nb) {
            bf16x8 kf0 = *(const bf16x8*)&Ks[nb * 1024 + lane * 8];
            bf16x8 kf1 = *(const bf16x8*)&Ks[nb * 1024 + 512 + lane * 8];
            f32x4 a; a[0] = a[1] = a[2] = a[3] = 0.f;
            a = MFMA16(kf0, qf0, a);
            a = MFMA16(kf1, qf1, a);
            sb[nb] = a;
        }

        // exp2, truncate to bf16, per-lane scalar sum, register repack
        u32 tr[4][4];
        #pragma unroll
        for (int nb = 0; nb < 4; ++nb)
            #pragma unroll
            for (int r = 0; r < 4; ++r) {
                float p = exp2f(sb[nb][r]);
                u32 bits = __float_as_uint(p) & 0xffff0000u;
                lsum += __uint_as_float(bits);
                tr[nb][r] = bits;
            }
        bf16x8 pa[2];
        #pragma unroll
        for (int mf = 0; mf < 2; ++mf) {
            union { bf16x8 v; u32 u[4]; } pk;
            pk.u[0] = (tr[2 * mf][0] >> 16) | tr[2 * mf][1];
            pk.u[1] = (tr[2 * mf][2] >> 16) | tr[2 * mf][3];
            pk.u[2] = (tr[2 * mf + 1][0] >> 16) | tr[2 * mf + 1][1];
            pk.u[3] = (tr[2 * mf + 1][2] >> 16) | tr[2 * mf + 1][3];
            pa[mf] = pk.v;
        }

        // O^T += V^T P^T : A = V^T frags (slot = actual key offset), B = pa
        #pragma unroll
        for (int nd = 0; nd < 4; ++nd)
            #pragma unroll
            for (int mf = 0; mf < 2; ++mf) {
                bf16x8 vf = *(const bf16x8*)&Vs[(nd * 2 + mf) * 512 + lane * 8];
                oacc[nd] = MFMA16(vf, pa[mf], oacc[nd]);
            }
    }

    // total = sum over 4 quads (all in-lane values are for query n_)
    float s = lsum;
    s += __shfl_xor(s, 16);
    s += __shfl_xor(s, 32);
    const float inv = 1.f / s;

    // epilogue: O^T[dk=nd*16+quad*4+r][query=n_] -> eb[query-local][dk]
    __syncthreads();
    u16* eb = SM + w * 1152;   // [16][72]
    #pragma unroll
    for (int nd = 0; nd < 4; ++nd) {
        uint2 uv;
        uv.x = (u32)f2bf(oacc[nd][0] * inv) |
               ((u32)f2bf(oacc[nd][1] * inv) << 16);
        uv.y = (u32)f2bf(oacc[nd][2] * inv) |
               ((u32)f2bf(oacc[nd][3] * inv) << 16);
        *(uint2*)&eb[n_ * 72 + nd * 16 + quad * 4] = uv;
    }
    __syncthreads();
    #pragma unroll
    for (int t = 0; t < 2; ++t) {
        int ii = lane + t * 64;
        int row = ii >> 3, c8 = (ii & 7) * 8;
        *(bf16x8*)&obf[((size_t)b * S_ + i0 + w * 16 + row) * ND + hd * DK + c8] =
            *(const bf16x8*)&eb[row * 72 + c8];
    }
}

// ---------------------------------------------------------------------------
// Out projection: A = woT (M=c=64), B = obf (N=s=128), BK=128.
// XCD swizzle: the 4 c0-blocks sharing one obf slice land on one XCD.
// C[c][s] layout -> direct coalesced stores out[b][c][s] (+bias+residual).
// ---------------------------------------------------------------------------
__global__ __launch_bounds__(256) void out_proj_mfma(
    const u16* __restrict__ obf, const u16* __restrict__ woT,
    const float* __restrict__ bo, const float* __restrict__ x,
    float* __restrict__ out)
{
    __shared__ __align__(16) u16 SM[24576];   // Bs 16384 (128x128) + As 8192 (64x128)
    u16* Bs = SM;
    u16* As = SM + 16384;

    const int tid = threadIdx.x;
    const int w = tid >> 6, lane = tid & 63;
    const int n_ = lane & 15, quad = lane >> 4;

    // swizzle: 512 blocks = 8 xcd x (4 c0 x 16 sb-group)
    const int id = blockIdx.x;
    const int xcd = id & 7, g = id >> 3;
    const int c0 = (g % 4) * 64;
    const int sbi = xcd * 16 + g / 4;        // [0,128)
    const int s0 = (sbi & 7) * 128, b = sbi >> 3;

    const u16* ar  = woT + (size_t)(c0 + w * 16 + n_) * ND + quad * 8;
    const u16* br0 = obf + ((size_t)b * S_ + s0 + (2 * w + 0) * 16 + n_) * ND + quad * 8;
    const u16* br1 = obf + ((size_t)b * S_ + s0 + (2 * w + 1) * 16 + n_) * ND + quad * 8;

    f32x4 acc[2][4];
    #pragma unroll
    for (int nf = 0; nf < 2; ++nf)
        #pragma unroll
        for (int mb = 0; mb < 4; ++mb)
            #pragma unroll
            for (int r = 0; r < 4; ++r) acc[nf][mb][r] = 0.f;

    #pragma unroll
    for (int kb = 0; kb < 2; ++kb) {
        const int kcb = kb * 128;
        __syncthreads();
        #pragma unroll
        for (int kc = 0; kc < 4; ++kc) {
            stage16(ar  + kcb + kc * 32, As + (w * 4 + kc) * 512);
            stage16(br0 + kcb + kc * 32, Bs + ((2 * w + 0) * 4 + kc) * 512);
            stage16(br1 + kcb + kc * 32, Bs + ((2 * w + 1) * 4 + kc) * 512);
        }
        __syncthreads();
        #pragma unroll
        for (int kc = 0; kc < 4; ++kc) {
            bf16x8 bf0 = *(const bf16x8*)&Bs[((2 * w + 0) * 4 + kc) * 512 + lane * 8];
            bf16x8 bf1 = *(const bf16x8*)&Bs[((2 * w + 1) * 4 + kc) * 512 + lane * 8];
            #pragma unroll
            for (int mb = 0; mb < 4; ++mb) {
                bf16x8 af = *(const bf16x8*)&As[(mb * 4 + kc) * 512 + lane * 8];
                acc[0][mb] = MFMA16(af, bf0, acc[0][mb]);
                acc[1][mb] = MFMA16(af, bf1, acc[1][mb]);
            }
        }
    }

    // direct epilogue: c = c0+mb*16+quad*4+r, s = s0+w*32+nf*16+n_
    #pragma unroll
    for (int mb = 0; mb < 4; ++mb)
        #pragma unroll
        for (int r = 0; r < 4; ++r) {
            int c = c0 + mb * 16 + quad * 4 + r;
            float bias = bo[c];
            #pragma unroll
            for (int nf = 0; nf < 2; ++nf) {
                size_t idx = ((size_t)b * C_ + c) * S_ + s0 + w * 32 + nf * 16 + n_;
                out[idx] = acc[nf][mb][r] + bias + x[idx];
            }
        }
}

// ---------------------------------------------------------------------------
extern "C" void kernel_launch(void* const* d_in, const int* in_sizes, int n_in,
                              void* d_out, int out_size, void* d_ws, size_t ws_size,
                              hipStream_t stream) {
    const float* x  = (const float*)d_in[0];
    const float* wp = (const float*)d_in[1];
    const float* bp = (const float*)d_in[2];
    const float* wo = (const float*)d_in[3];
    const float* bo = (const float*)d_in[4];
    float* out = (float*)d_out;

    const size_t QKV_E = (size_t)B_ * NH * S_ * DK;   // 4 Mi
    u16* q   = (u16*)d_ws;
    u16* kk  = q   + QKV_E;
    u16* vtp = kk  + QKV_E;
    u16* obf = vtp + QKV_E;                            // B*S*ND
    u16* xt  = obf + (size_t)B_ * S_ * ND;             // B*S*C
    u16* wpT = xt  + (size_t)B_ * S_ * C_;             // P3*C
    u16* woT = wpT + (size_t)P3 * C_;                  // C*ND

    transpose_cvt<<<dim3(S_ / 64, C_ / 64, B_), 256, 0, stream>>>(x, xt, C_, S_);
    transpose_w  <<<dim3(12, 4, 2),             256, 0, stream>>>(wp, wpT, wo, woT);
    qkv_mfma     <<<dim3(1536), 256, 0, stream>>>(xt, wpT, bp, q, kk, vtp);
    attn_mfma    <<<dim3(1024), 256, 0, stream>>>(q, kk, vtp, obf);
    out_proj_mfma<<<dim3(512),  256, 0, stream>>>(obf, woT, bo, x, out);
}